// Round 4
// baseline (183.028 us; speedup 1.0000x reference)
//
#include <hip/hip_runtime.h>
#include <math.h>
#include <stdint.h>

#define NB 4
#define CC 256
#define HWD 4096

typedef __attribute__((ext_vector_type(8))) short bf16x8;
typedef __attribute__((ext_vector_type(4))) float f32x4;

#define VMW8()  asm volatile("s_waitcnt vmcnt(8)" ::: "memory")
#define VMW0()  asm volatile("s_waitcnt vmcnt(0)" ::: "memory")
#define LGKM0() asm volatile("s_waitcnt lgkmcnt(0)" ::: "memory")
#define SCHED0() __builtin_amdgcn_sched_barrier(0)
#define SBAR()  __builtin_amdgcn_s_barrier()

__device__ __forceinline__ void gload16(const void* g, void* l) {
    using GP = const __attribute__((address_space(1))) uint32_t*;
    using LP = __attribute__((address_space(3))) uint32_t*;
    __builtin_amdgcn_global_load_lds((GP)g, (LP)l, 16, 0, 0);
}

// sum over each 16-lane DPP row; result valid in lane (rl==15) of each row
__device__ __forceinline__ float dpp_rowsum16(float v) {
    v += __int_as_float(__builtin_amdgcn_update_dpp(0, __float_as_int(v), 0x111, 0xf, 0xf, true));
    v += __int_as_float(__builtin_amdgcn_update_dpp(0, __float_as_int(v), 0x112, 0xf, 0xf, true));
    v += __int_as_float(__builtin_amdgcn_update_dpp(0, __float_as_int(v), 0x114, 0xf, 0xf, true));
    v += __int_as_float(__builtin_amdgcn_update_dpp(0, __float_as_int(v), 0x118, 0xf, 0xf, true));
    return v;
}

// ---------------- kernel 1: per-pixel L2 norm + scale + bf16 + transpose ----------------
__global__ __launch_bounds__(512) void normcvt(
    const float* __restrict__ rgb, const float* __restrict__ ir,
    ushort* __restrict__ Abf, ushort* __restrict__ Bbf)
{
    __shared__ float ssbuf[8][64];
    __shared__ float rnl[64];
    const float* src = blockIdx.y ? ir : rgb;
    ushort* dst = blockIdx.y ? Bbf : Abf;
    const int t = threadIdx.x;
    const int p = t & 63, sg = t >> 6;
    const int P = blockIdx.x * 64 + p;
    const int n = P >> 12, pl = P & (HWD - 1);
    const float* base = src + ((size_t)n * CC) * HWD + pl;
    const int c0 = sg * 32;

    float x[32];
    float ss = 0.f;
#pragma unroll
    for (int i = 0; i < 32; ++i) {
        x[i] = base[(size_t)(c0 + i) * HWD];
        ss = fmaf(x[i], x[i], ss);
    }
    ssbuf[sg][p] = ss;
    __syncthreads();
    if (t < 64) {
        float s2 = 0.f;
#pragma unroll
        for (int g = 0; g < 8; ++g) s2 += ssbuf[g][t];
        rnl[t] = 1.0f / fmaxf(sqrtf(s2), 1e-12f);
    }
    __syncthreads();
    const float rn = rnl[p];

    uint pk[16];
#pragma unroll
    for (int i = 0; i < 16; ++i) {
        float x0 = x[2 * i] * rn;
        float x1 = x[2 * i + 1] * rn;
        uint u0 = __float_as_uint(x0); u0 += 0x7fffu + ((u0 >> 16) & 1u);  // RNE bf16
        uint u1 = __float_as_uint(x1); u1 += 0x7fffu + ((u1 >> 16) & 1u);
        pk[i] = (u0 >> 16) | (u1 & 0xffff0000u);
    }
    uint4* o = (uint4*)(dst + (size_t)P * CC + c0);
#pragma unroll
    for (int k = 0; k < 4; ++k)
        o[k] = make_uint4(pk[4 * k], pk[4 * k + 1], pk[4 * k + 2], pk[4 * k + 3]);
}

// ---------------- kernel 2: 256x256-tile bf16 MFMA GEMM, counted-vmcnt pipeline ----------------
// 8 waves (2 x 4 of 128x64), BK=64, 2-deep prefetch, never vmcnt(0) mid-loop.
__global__ __launch_bounds__(512, 2) void gemm_mfma(
    const ushort* __restrict__ Abf, const ushort* __restrict__ Bbf,
    const int* __restrict__ rmask, const int* __restrict__ imask,
    float* __restrict__ num_r, float* __restrict__ den_r,
    float* __restrict__ num_i, float* __restrict__ den_i)
{
    __shared__ __align__(16) ushort As[2][256][64];
    __shared__ __align__(16) ushort Bs[2][256][64];

    // XCD-aware bijective swizzle: 1024 blocks, 128 consecutive per XCD
    const int id = blockIdx.x;
    const int swz = (id & 7) * 128 + (id >> 3);
    const int n  = swz >> 8;
    const int pq = swz & 255;
    const int p0 = (pq >> 4) * 256;
    const int q0 = (pq & 15) * 256;

    const int t = threadIdx.x;
    const int lane = t & 63;
    const int wv = t >> 6;
    const int wr = wv >> 2, wc = wv & 3;     // 2 x 4 wave grid
    const int kg = lane >> 4, rl = lane & 15;

    const ushort* Ab = Abf + ((size_t)n * HWD + p0) * CC;
    const ushort* Bb = Bbf + ((size_t)n * HWD + q0) * CC;

    f32x4 acc[8][4];
#pragma unroll
    for (int mi = 0; mi < 8; ++mi)
#pragma unroll
        for (int ni = 0; ni < 4; ++ni) acc[mi][ni] = (f32x4){0.f, 0.f, 0.f, 0.f};

    // stage one 256x64 K-tile of A and B: 2048 16B-slots each, 512 threads -> 4+4 loads/thread
    // global chunk pre-swizzled g = pos ^ (r&7); LDS written linearly (wave base + lane*16)
    auto stage = [&](int buf, int c0) {
#pragma unroll
        for (int it = 0; it < 4; ++it) {
            int slot = it * 512 + t;
            int r = slot >> 3;
            int g = (slot & 7) ^ (r & 7);
            size_t go = (size_t)r * CC + c0 + g * 8;
            char* la = ((char*)As[buf]) + it * 8192 + wv * 1024;
            char* lb = ((char*)Bs[buf]) + it * 8192 + wv * 1024;
            gload16(Ab + go, la);
            gload16(Bb + go, lb);
        }
    };

    stage(0, 0);      // 8 loads/thread in flight
    stage(1, 64);     // 16 in flight
    SCHED0();

#define KITER(KT, VMWAIT, DO_RESTAGE)                                          \
    {                                                                          \
        VMWAIT;                                                                \
        SCHED0();                                                              \
        SBAR();                                                                \
        SCHED0();                                                              \
        const int buf = (KT) & 1;                                              \
        bf16x8 a0[8], b0[4], a1[8], b1[4];                                     \
        _Pragma("unroll")                                                      \
        for (int mi = 0; mi < 8; ++mi) {                                       \
            int r = wr * 128 + mi * 16 + rl;                                   \
            a0[mi] = *(const bf16x8*)&As[buf][r][(kg ^ (r & 7)) * 8];          \
        }                                                                      \
        _Pragma("unroll")                                                      \
        for (int ni = 0; ni < 4; ++ni) {                                       \
            int r = wc * 64 + ni * 16 + rl;                                    \
            b0[ni] = *(const bf16x8*)&Bs[buf][r][(kg ^ (r & 7)) * 8];          \
        }                                                                      \
        __builtin_amdgcn_s_setprio(1);                                         \
        _Pragma("unroll")                                                      \
        for (int mi = 0; mi < 8; ++mi)                                         \
            _Pragma("unroll")                                                  \
            for (int ni = 0; ni < 4; ++ni)                                     \
                acc[mi][ni] = __builtin_amdgcn_mfma_f32_16x16x32_bf16(         \
                    a0[mi], b0[ni], acc[mi][ni], 0, 0, 0);                     \
        __builtin_amdgcn_s_setprio(0);                                         \
        _Pragma("unroll")                                                      \
        for (int mi = 0; mi < 8; ++mi) {                                       \
            int r = wr * 128 + mi * 16 + rl;                                   \
            a1[mi] = *(const bf16x8*)&As[buf][r][((4 + kg) ^ (r & 7)) * 8];    \
        }                                                                      \
        _Pragma("unroll")                                                      \
        for (int ni = 0; ni < 4; ++ni) {                                       \
            int r = wc * 64 + ni * 16 + rl;                                    \
            b1[ni] = *(const bf16x8*)&Bs[buf][r][((4 + kg) ^ (r & 7)) * 8];    \
        }                                                                      \
        LGKM0();                                                               \
        SCHED0();                                                              \
        SBAR();                                                                \
        SCHED0();                                                              \
        DO_RESTAGE;                                                            \
        __builtin_amdgcn_s_setprio(1);                                         \
        _Pragma("unroll")                                                      \
        for (int mi = 0; mi < 8; ++mi)                                         \
            _Pragma("unroll")                                                  \
            for (int ni = 0; ni < 4; ++ni)                                     \
                acc[mi][ni] = __builtin_amdgcn_mfma_f32_16x16x32_bf16(         \
                    a1[mi], b1[ni], acc[mi][ni], 0, 0, 0);                     \
        __builtin_amdgcn_s_setprio(0);                                         \
        SCHED0();                                                              \
    }

    KITER(0, VMW8(), stage(0, 128));
    KITER(1, VMW8(), stage(1, 192));
    KITER(2, VMW8(), );
    KITER(3, VMW0(), );
#undef KITER

    // ---- epilogue: clamp, exp, mask, reduce (labels loaded only here) ----
    const int* rmp = rmask + (size_t)n * HWD + p0 + wr * 128;
    const int* imp = imask + (size_t)n * HWD + q0 + wc * 64;
    int clab[4];
#pragma unroll
    for (int ni = 0; ni < 4; ++ni) clab[ni] = imp[ni * 16 + rl];

    const float SC = 28.853900817779268f;   // 20 * log2(e)
    float cn[4] = {0.f, 0.f, 0.f, 0.f}, cd[4] = {0.f, 0.f, 0.f, 0.f};

#pragma unroll
    for (int mi = 0; mi < 8; ++mi) {
        int4 r4 = *(const int4*)(rmp + mi * 16 + kg * 4);
        int rlab[4] = {r4.x, r4.y, r4.z, r4.w};
        float rn4[4] = {0.f, 0.f, 0.f, 0.f}, rd4[4] = {0.f, 0.f, 0.f, 0.f};
#pragma unroll
        for (int ni = 0; ni < 4; ++ni) {
#pragma unroll
            for (int j = 0; j < 4; ++j) {
                float s = fminf(fmaxf(acc[mi][ni][j], -1.f), 1.f);
                float e = exp2f(s * SC);
                rd4[j] += e;
                cd[ni] += e;
                bool m = (rlab[j] == clab[ni]);
                rn4[j] += m ? e : 0.f;
                cn[ni] += m ? e : 0.f;
            }
        }
#pragma unroll
        for (int j = 0; j < 4; ++j) {
            rn4[j] = dpp_rowsum16(rn4[j]);
            rd4[j] = dpp_rowsum16(rd4[j]);
        }
        if (rl == 15) {
            size_t row = (size_t)n * HWD + p0 + wr * 128 + mi * 16 + kg * 4;
#pragma unroll
            for (int j = 0; j < 4; ++j) {
                atomicAdd(&num_r[row + j], rn4[j]);
                atomicAdd(&den_r[row + j], rd4[j]);
            }
        }
    }
#pragma unroll
    for (int ni = 0; ni < 4; ++ni) {
        cn[ni] += __shfl_xor(cn[ni], 16); cn[ni] += __shfl_xor(cn[ni], 32);
        cd[ni] += __shfl_xor(cd[ni], 16); cd[ni] += __shfl_xor(cd[ni], 32);
    }
    if (kg == 0) {
#pragma unroll
        for (int ni = 0; ni < 4; ++ni) {
            size_t col = (size_t)n * HWD + q0 + wc * 64 + ni * 16 + rl;
            atomicAdd(&num_i[col], cn[ni]);
            atomicAdd(&den_i[col], cd[ni]);
        }
    }
}

// ---------------- kernel 3: loss entries + global reduce ----------------
__global__ __launch_bounds__(256) void loss_reduce(
    const float* __restrict__ num_r, const float* __restrict__ den_r,
    const float* __restrict__ num_i, const float* __restrict__ den_i,
    const int* __restrict__ rmask, const int* __restrict__ imask,
    float* __restrict__ accum)
{
    __shared__ float sbuf[2][4];
    int idx = blockIdx.x * 256 + threadIdx.x;
    float num, den; int fg;
    if (idx < NB * HWD) {
        num = num_r[idx]; den = den_r[idx]; fg = rmask[idx] > 0;
    } else {
        int k = idx - NB * HWD;
        num = num_i[k]; den = den_i[k]; fg = imask[k] > 0;
    }
    float v = 0.f, cnt = 0.f;
    if (fg && num > 0.f) {
        float r = num / (den + 1e-6f);
        v = -__logf(r);
        cnt = 1.f;
    }
#pragma unroll
    for (int m = 1; m <= 32; m <<= 1) {
        v += __shfl_xor(v, m);
        cnt += __shfl_xor(cnt, m);
    }
    int lane = threadIdx.x & 63, wave = threadIdx.x >> 6;
    if (lane == 0) { sbuf[0][wave] = v; sbuf[1][wave] = cnt; }
    __syncthreads();
    if (threadIdx.x == 0) {
        atomicAdd(&accum[0], sbuf[0][0] + sbuf[0][1] + sbuf[0][2] + sbuf[0][3]);
        atomicAdd(&accum[1], sbuf[1][0] + sbuf[1][1] + sbuf[1][2] + sbuf[1][3]);
    }
}

__global__ void finalize(const float* __restrict__ accum, float* __restrict__ out) {
    out[0] = accum[0] / fmaxf(accum[1], 1.0f);
}

// ---------------- launch ----------------
extern "C" void kernel_launch(void* const* d_in, const int* in_sizes, int n_in,
                              void* d_out, int out_size, void* d_ws, size_t ws_size,
                              hipStream_t stream) {
    const float* rgb = (const float*)d_in[0];
    const float* ir  = (const float*)d_in[1];
    const int* rm = (const int*)d_in[2];
    const int* im = (const int*)d_in[3];
    float* out = (float*)d_out;

    const size_t NP = (size_t)NB * HWD;          // 16384 pixels
    const size_t NE = NP * CC;                   // 4M bf16 per array
    ushort* Abf = (ushort*)d_ws;
    ushort* Bbf = Abf + NE;
    float* num_r = (float*)(Bbf + NE);
    float* den_r = num_r + NP;
    float* num_i = den_r + NP;
    float* den_i = num_i + NP;
    float* accum = den_i + NP;                   // 2 floats

    hipMemsetAsync(num_r, 0, (4 * NP + 2) * sizeof(float), stream);

    normcvt<<<dim3(NP / 64, 2), 512, 0, stream>>>(rgb, ir, Abf, Bbf);
    gemm_mfma<<<dim3(1024), 512, 0, stream>>>(
        Abf, Bbf, rm, im, num_r, den_r, num_i, den_i);
    loss_reduce<<<(2 * NP) / 256, 256, 0, stream>>>(num_r, den_r, num_i, den_i, rm, im, accum);
    finalize<<<1, 1, 0, stream>>>(accum, out);
}

// Round 5
// 93.491 us; speedup vs baseline: 1.9577x; 1.9577x over previous
//
#include <hip/hip_runtime.h>
#include <math.h>
#include <stdint.h>

#define NB 4
#define CC 256
#define HWD 4096
#define NPIX (NB * HWD)

typedef __attribute__((ext_vector_type(8))) short bf16x8;
typedef __attribute__((ext_vector_type(4))) float f32x4;

#define VMW8()  asm volatile("s_waitcnt vmcnt(8)" ::: "memory")
#define VMW0()  asm volatile("s_waitcnt vmcnt(0)" ::: "memory")
#define LGKM0() asm volatile("s_waitcnt lgkmcnt(0)" ::: "memory")
#define SCHED0() __builtin_amdgcn_sched_barrier(0)
#define SBAR()  __builtin_amdgcn_s_barrier()

__device__ __forceinline__ void gload16(const void* g, void* l) {
    using GP = const __attribute__((address_space(1))) uint32_t*;
    using LP = __attribute__((address_space(3))) uint32_t*;
    __builtin_amdgcn_global_load_lds((GP)g, (LP)l, 16, 0, 0);
}

// sum over each 16-lane DPP row; result valid in lane (rl==15) of each row
__device__ __forceinline__ float dpp_rowsum16(float v) {
    v += __int_as_float(__builtin_amdgcn_update_dpp(0, __float_as_int(v), 0x111, 0xf, 0xf, true));
    v += __int_as_float(__builtin_amdgcn_update_dpp(0, __float_as_int(v), 0x112, 0xf, 0xf, true));
    v += __int_as_float(__builtin_amdgcn_update_dpp(0, __float_as_int(v), 0x114, 0xf, 0xf, true));
    v += __int_as_float(__builtin_amdgcn_update_dpp(0, __float_as_int(v), 0x118, 0xf, 0xf, true));
    return v;
}

// ---------------- kernel 1: per-pixel L2 norm + scale + bf16 + transpose ----------------
__global__ __launch_bounds__(512) void normcvt(
    const float* __restrict__ rgb, const float* __restrict__ ir,
    ushort* __restrict__ Abf, ushort* __restrict__ Bbf)
{
    __shared__ float ssbuf[8][64];
    __shared__ float rnl[64];
    const float* src = blockIdx.y ? ir : rgb;
    ushort* dst = blockIdx.y ? Bbf : Abf;
    const int t = threadIdx.x;
    const int p = t & 63, sg = t >> 6;
    const int P = blockIdx.x * 64 + p;
    const int n = P >> 12, pl = P & (HWD - 1);
    const float* base = src + ((size_t)n * CC) * HWD + pl;
    const int c0 = sg * 32;

    float x[32];
    float ss = 0.f;
#pragma unroll
    for (int i = 0; i < 32; ++i) {
        x[i] = base[(size_t)(c0 + i) * HWD];
        ss = fmaf(x[i], x[i], ss);
    }
    ssbuf[sg][p] = ss;
    __syncthreads();
    if (t < 64) {
        float s2 = 0.f;
#pragma unroll
        for (int g = 0; g < 8; ++g) s2 += ssbuf[g][t];
        rnl[t] = 1.0f / fmaxf(sqrtf(s2), 1e-12f);
    }
    __syncthreads();
    const float rn = rnl[p];

    uint pk[16];
#pragma unroll
    for (int i = 0; i < 16; ++i) {
        float x0 = x[2 * i] * rn;
        float x1 = x[2 * i + 1] * rn;
        uint u0 = __float_as_uint(x0); u0 += 0x7fffu + ((u0 >> 16) & 1u);  // RNE bf16
        uint u1 = __float_as_uint(x1); u1 += 0x7fffu + ((u1 >> 16) & 1u);
        pk[i] = (u0 >> 16) | (u1 & 0xffff0000u);
    }
    uint4* o = (uint4*)(dst + (size_t)P * CC + c0);
#pragma unroll
    for (int k = 0; k < 4; ++k)
        o[k] = make_uint4(pk[4 * k], pk[4 * k + 1], pk[4 * k + 2], pk[4 * k + 3]);
}

// ---------------- kernel 2: 128x128-tile bf16 MFMA GEMM, counted-vmcnt, partial-sum epilogue ----
// 4 waves (2x2 of 64x64), BK=64, 2-deep prefetch (vmcnt(8), never 0 mid-loop), no atomics.
__global__ __launch_bounds__(256, 2) void gemm_mfma(
    const ushort* __restrict__ Abf, const ushort* __restrict__ Bbf,
    const int* __restrict__ rmask, const int* __restrict__ imask,
    float2* __restrict__ prow, float2* __restrict__ pcol)
{
    __shared__ __align__(16) ushort As[2][128][64];
    __shared__ __align__(16) ushort Bs[2][128][64];

    const int n  = blockIdx.z;
    // XCD-aware bijective swizzle within the 32x32 slice (1024 % 8 == 0)
    const int lin = blockIdx.y * 32 + blockIdx.x;
    const int swz = (lin & 7) * 128 + (lin >> 3);
    const int qt = swz & 31, pt = swz >> 5;
    const int q0 = qt * 128, p0 = pt * 128;

    const int t  = threadIdx.x;
    const int lane = t & 63;
    const int wv = t >> 6, wr = wv >> 1, wc = wv & 1;
    const int kg = lane >> 4, rl = lane & 15;

    const ushort* Ab = Abf + ((size_t)n * HWD + p0) * CC;
    const ushort* Bb = Bbf + ((size_t)n * HWD + q0) * CC;

    f32x4 acc[4][4];
#pragma unroll
    for (int mi = 0; mi < 4; ++mi)
#pragma unroll
        for (int ni = 0; ni < 4; ++ni) acc[mi][ni] = (f32x4){0.f, 0.f, 0.f, 0.f};

    // stage one 128x64 K-tile of A and B: 1024 16B-slots each, 256 threads -> 8 gload16/thread
    // global chunk pre-swizzled g = pos ^ (r&7); LDS written linearly (wave base + lane*16)
    auto stage = [&](int buf, int c0) {
#pragma unroll
        for (int it = 0; it < 4; ++it) {
            int slot = it * 256 + t;
            int r = slot >> 3, pos = slot & 7;
            int g = pos ^ (r & 7);
            size_t go = (size_t)r * CC + c0 + g * 8;
            char* la = ((char*)As[buf]) + it * 4096 + (t & 192) * 16;
            char* lb = ((char*)Bs[buf]) + it * 4096 + (t & 192) * 16;
            gload16(Ab + go, la);
            gload16(Bb + go, lb);
        }
    };

    stage(0, 0);      // 8 loads/thread in flight
    stage(1, 64);     // 16 in flight
    SCHED0();

#define KITER(BUF, VMWAIT, RESTAGE)                                            \
    {                                                                          \
        VMWAIT;                                                                \
        SCHED0();                                                              \
        SBAR();                                                                \
        SCHED0();                                                              \
        bf16x8 a[4][2], b[4][2];                                               \
        _Pragma("unroll")                                                      \
        for (int mi = 0; mi < 4; ++mi) {                                       \
            int r = wr * 64 + mi * 16 + rl;                                    \
            a[mi][0] = *(const bf16x8*)&As[BUF][r][((kg) ^ (r & 7)) * 8];      \
            a[mi][1] = *(const bf16x8*)&As[BUF][r][((4 + kg) ^ (r & 7)) * 8];  \
        }                                                                      \
        _Pragma("unroll")                                                      \
        for (int ni = 0; ni < 4; ++ni) {                                       \
            int r = wc * 64 + ni * 16 + rl;                                    \
            b[ni][0] = *(const bf16x8*)&Bs[BUF][r][((kg) ^ (r & 7)) * 8];      \
            b[ni][1] = *(const bf16x8*)&Bs[BUF][r][((4 + kg) ^ (r & 7)) * 8];  \
        }                                                                      \
        LGKM0();                                                               \
        SCHED0();                                                              \
        SBAR();                                                                \
        SCHED0();                                                              \
        RESTAGE;                                                               \
        __builtin_amdgcn_s_setprio(1);                                         \
        _Pragma("unroll")                                                      \
        for (int ks = 0; ks < 2; ++ks)                                         \
            _Pragma("unroll")                                                  \
            for (int mi = 0; mi < 4; ++mi)                                     \
                _Pragma("unroll")                                              \
                for (int ni = 0; ni < 4; ++ni)                                 \
                    acc[mi][ni] = __builtin_amdgcn_mfma_f32_16x16x32_bf16(     \
                        a[mi][ks], b[ni][ks], acc[mi][ni], 0, 0, 0);           \
        __builtin_amdgcn_s_setprio(0);                                         \
        SCHED0();                                                              \
    }

    KITER(0, VMW8(), stage(0, 128));
    KITER(1, VMW8(), stage(1, 192));
    KITER(0, VMW8(), );
    KITER(1, VMW0(), );
#undef KITER

    // ---- epilogue: clamp, exp, mask, block-local reduce, partial store (no atomics) ----
    const int* rmp = rmask + (size_t)n * HWD + p0 + wr * 64;
    const int* imp = imask + (size_t)n * HWD + q0 + wc * 64;
    int clab[4];
#pragma unroll
    for (int ni = 0; ni < 4; ++ni) clab[ni] = imp[ni * 16 + rl];

    // LDS scratch aliasing As (all LDS reads completed before last barrier)
    float* rb = (float*)As;      // [wc][nd][128 rows] = 512 floats
    float* cb = rb + 512;        // [wr][nd][128 cols] = 512 floats

    const float SC = 28.853900817779268f;   // 20 * log2(e)
    float cn[4] = {0.f, 0.f, 0.f, 0.f}, cd[4] = {0.f, 0.f, 0.f, 0.f};

#pragma unroll
    for (int mi = 0; mi < 4; ++mi) {
        int4 r4 = *(const int4*)(rmp + mi * 16 + kg * 4);
        int rlab[4] = {r4.x, r4.y, r4.z, r4.w};
        float rn4[4] = {0.f, 0.f, 0.f, 0.f}, rd4[4] = {0.f, 0.f, 0.f, 0.f};
#pragma unroll
        for (int ni = 0; ni < 4; ++ni) {
#pragma unroll
            for (int j = 0; j < 4; ++j) {
                float s = fminf(fmaxf(acc[mi][ni][j], -1.f), 1.f);
                float e = exp2f(s * SC);
                rd4[j] += e;
                cd[ni] += e;
                bool m = (rlab[j] == clab[ni]);
                rn4[j] += m ? e : 0.f;
                cn[ni] += m ? e : 0.f;
            }
        }
#pragma unroll
        for (int j = 0; j < 4; ++j) {
            rn4[j] = dpp_rowsum16(rn4[j]);
            rd4[j] = dpp_rowsum16(rd4[j]);
        }
        if (rl == 15) {
            int row = wr * 64 + mi * 16 + kg * 4;
#pragma unroll
            for (int j = 0; j < 4; ++j) {
                rb[(wc * 2 + 0) * 128 + row + j] = rn4[j];
                rb[(wc * 2 + 1) * 128 + row + j] = rd4[j];
            }
        }
    }
#pragma unroll
    for (int ni = 0; ni < 4; ++ni) {
        cn[ni] += __shfl_xor(cn[ni], 16); cn[ni] += __shfl_xor(cn[ni], 32);
        cd[ni] += __shfl_xor(cd[ni], 16); cd[ni] += __shfl_xor(cd[ni], 32);
    }
    if (kg == 0) {
#pragma unroll
        for (int ni = 0; ni < 4; ++ni) {
            int col = wc * 64 + ni * 16 + rl;
            cb[(wr * 2 + 0) * 128 + col] = cn[ni];
            cb[(wr * 2 + 1) * 128 + col] = cd[ni];
        }
    }
    __syncthreads();
    if (t < 128) {
        float2 r2 = make_float2(rb[t] + rb[256 + t], rb[128 + t] + rb[384 + t]);
        prow[(size_t)qt * NPIX + (size_t)n * HWD + p0 + t] = r2;
        float2 c2 = make_float2(cb[t] + cb[256 + t], cb[128 + t] + cb[384 + t]);
        pcol[(size_t)pt * NPIX + (size_t)n * HWD + q0 + t] = c2;
    }
}

// ---------------- kernel 3: reduce partials + loss entries + global reduce ----------------
__global__ __launch_bounds__(256) void loss_reduce(
    const float2* __restrict__ prow, const float2* __restrict__ pcol,
    const int* __restrict__ rmask, const int* __restrict__ imask,
    float* __restrict__ accum)
{
    __shared__ float sbuf[2][4];
    int idx = blockIdx.x * 256 + threadIdx.x;   // 0 .. 2*NPIX-1
    float num = 0.f, den = 0.f; int fg;
    if (idx < NPIX) {
        fg = rmask[idx] > 0;
#pragma unroll 8
        for (int q = 0; q < 32; ++q) {
            float2 v = prow[(size_t)q * NPIX + idx];
            num += v.x; den += v.y;
        }
    } else {
        int k = idx - NPIX;
        fg = imask[k] > 0;
#pragma unroll 8
        for (int p = 0; p < 32; ++p) {
            float2 v = pcol[(size_t)p * NPIX + k];
            num += v.x; den += v.y;
        }
    }
    float v = 0.f, cnt = 0.f;
    if (fg && num > 0.f) {
        float r = num / (den + 1e-6f);
        v = -__logf(r);
        cnt = 1.f;
    }
#pragma unroll
    for (int m = 1; m <= 32; m <<= 1) {
        v += __shfl_xor(v, m);
        cnt += __shfl_xor(cnt, m);
    }
    int lane = threadIdx.x & 63, wave = threadIdx.x >> 6;
    if (lane == 0) { sbuf[0][wave] = v; sbuf[1][wave] = cnt; }
    __syncthreads();
    if (threadIdx.x == 0) {
        atomicAdd(&accum[0], sbuf[0][0] + sbuf[0][1] + sbuf[0][2] + sbuf[0][3]);
        atomicAdd(&accum[1], sbuf[1][0] + sbuf[1][1] + sbuf[1][2] + sbuf[1][3]);
    }
}

__global__ void finalize(const float* __restrict__ accum, float* __restrict__ out) {
    out[0] = accum[0] / fmaxf(accum[1], 1.0f);
}

// ---------------- launch ----------------
extern "C" void kernel_launch(void* const* d_in, const int* in_sizes, int n_in,
                              void* d_out, int out_size, void* d_ws, size_t ws_size,
                              hipStream_t stream) {
    const float* rgb = (const float*)d_in[0];
    const float* ir  = (const float*)d_in[1];
    const int* rm = (const int*)d_in[2];
    const int* im = (const int*)d_in[3];
    float* out = (float*)d_out;

    const size_t NE = (size_t)NPIX * CC;         // 4M bf16 per array
    ushort* Abf = (ushort*)d_ws;
    ushort* Bbf = Abf + NE;
    float2* prow = (float2*)(Bbf + NE);          // 32 * NPIX float2 = 4 MB
    float2* pcol = prow + (size_t)32 * NPIX;     // 4 MB
    float* accum = (float*)(pcol + (size_t)32 * NPIX);  // 2 floats

    hipMemsetAsync(accum, 0, 2 * sizeof(float), stream);

    normcvt<<<dim3(NPIX / 64, 2), 512, 0, stream>>>(rgb, ir, Abf, Bbf);
    gemm_mfma<<<dim3(HWD / 128, HWD / 128, NB), 256, 0, stream>>>(
        Abf, Bbf, rm, im, prow, pcol);
    loss_reduce<<<(2 * NPIX) / 256, 256, 0, stream>>>(prow, pcol, rm, im, accum);
    finalize<<<1, 1, 0, stream>>>(accum, out);
}